// Round 4
// baseline (414.642 us; speedup 1.0000x reference)
//
#include <hip/hip_runtime.h>
#include <hip/hip_bf16.h>

// Problem constants
#define B_   4
#define NQ_  2048
#define NK_  2048
#define D_   1024
#define H_   16
#define DH_  64
#define SCALE_ 0.125f

typedef __attribute__((ext_vector_type(8))) __bf16 bf16x8;
typedef __attribute__((ext_vector_type(4))) float  f32x4;

typedef const __attribute__((address_space(1))) unsigned int* gas1p;
typedef __attribute__((address_space(3))) unsigned int*       las3p;

__device__ __forceinline__ f32x4 mfma16(bf16x8 a, bf16x8 b, f32x4 c) {
  return __builtin_amdgcn_mfma_f32_16x16x32_bf16(a, b, c, 0, 0, 0);
}
__device__ __forceinline__ void gload_lds16(const void* g, void* l) {
  __builtin_amdgcn_global_load_lds((gas1p)g, (las3p)l, 16, 0, 0);
}
__device__ __forceinline__ float nn_(float x) {
  if (__builtin_isnan(x)) return 0.0f;
  if (__builtin_isinf(x)) return x > 0.f ? 3.402823466e38f : -3.402823466e38f;
  return x;
}
__device__ __forceinline__ float exp2_(float x) {
#if __has_builtin(__builtin_amdgcn_exp2f)
  return __builtin_amdgcn_exp2f(x);
#else
  return __expf(x * 0.69314718056f);
#endif
}

// ---------------- fp32 -> bf16 convert (vectorized) ----------------
__global__ __launch_bounds__(256) void cvt_bf16_k(const float* __restrict__ s,
                                                  __bf16* __restrict__ d, int n) {
  int i = (blockIdx.x * blockDim.x + threadIdx.x) << 2;
  if (i >= n) return;
  float4 v = *(const float4*)(s + i);
  __bf16 o[4] __attribute__((aligned(8))) = {(__bf16)v.x, (__bf16)v.y, (__bf16)v.z, (__bf16)v.w};
  *(uint2*)(d + i) = *(uint2*)o;
}

// ------------- weight transpose + convert + scale: src[K][N] -> dst[N][K] -------------
__global__ __launch_bounds__(256) void transpose_cvt_k(const float* __restrict__ src,
                                                       __bf16* __restrict__ dst,
                                                       int K, int N, float scale) {
  __shared__ float t[32][33];
  int n0 = blockIdx.x * 32, k0 = blockIdx.y * 32;
  int x = threadIdx.x, y0 = threadIdx.y;
  for (int yy = y0; yy < 32; yy += 8)
    t[yy][x] = src[(size_t)(k0 + yy) * N + n0 + x];
  __syncthreads();
  for (int yy = y0; yy < 32; yy += 8)
    dst[(size_t)(n0 + yy) * K + k0 + x] = (__bf16)(t[x][yy] * scale);
}

// ---------------- 256-tile 4-phase GEMM: C[M][N] = A[M][K] @ Bt[N][K]^T + bias ----------------
// BM=256, BK=64, 512 threads = 8 waves (2M x 4N), per-wave output 128 x BN/4.
// Per K-tile: 4 phases (quadrant rh,ch). Phase = {ds_read quadrant frags | stage next tile
// into buf^1 | barrier | lgkmcnt(0) | MFMA cluster | barrier}. A-frags cached across the two
// ch-phases of each rh. Staging always targets the buffer NOT being read (race-free);
// boundary s_waitcnt vmcnt(0) once per K-tile, stages front-loaded >=2 phases earlier.
template <int BN, bool OUT_BF16, bool RES>
__global__ __launch_bounds__(512, 2) void gemm256_k(const __bf16* __restrict__ A,
                                                    const __bf16* __restrict__ Bt,
                                                    const float* __restrict__ bias, float bscale,
                                                    const float* __restrict__ res,
                                                    void* __restrict__ out,
                                                    int M, int N, int K) {
  constexpr int BM = 256, BK = 64;
  constexpr int ALOADS = 4;                  // per-thread gload_lds per A tile (32KB/512/16B)
  constexpr int BLOADS = (BN == 256) ? 4 : 2;
  constexpr int NRq = BN / 128;              // B frags per quadrant (256->2, 128->1)
  __shared__ __attribute__((aligned(16))) __bf16 Al[2][BM * BK];
  __shared__ __attribute__((aligned(16))) __bf16 Bl[2][BN * BK];

  const int tid = threadIdx.x, lane = tid & 63, wid = tid >> 6;
  const int wr = wid >> 2, wc = wid & 3;
  const int g = lane >> 4, lr = lane & 15;
  const int m0 = blockIdx.y * BM, n0 = blockIdx.x * BN;

  auto stageA = [&](int dbuf, int k0, int j) {
    int c = j * 512 + tid;
    gload_lds16(A + (size_t)(m0 + (c >> 3)) * K + k0 + ((c & 7) << 3),
                (char*)&Al[dbuf][0] + ((j * 512 + (wid << 6)) << 4));
  };
  auto stageB = [&](int dbuf, int k0, int j) {
    int c = j * 512 + tid;
    gload_lds16(Bt + (size_t)(n0 + (c >> 3)) * K + k0 + ((c & 7) << 3),
                (char*)&Bl[dbuf][0] + ((j * 512 + (wid << 6)) << 4));
  };

  const f32x4 zero4 = {0.f, 0.f, 0.f, 0.f};
  f32x4 acc[8][BN / 64];
#pragma unroll
  for (int m = 0; m < 8; m++)
#pragma unroll
    for (int n = 0; n < BN / 64; n++) acc[m][n] = zero4;

  // prologue: stage tile 0
#pragma unroll
  for (int j = 0; j < ALOADS; ++j) stageA(0, 0, j);
#pragma unroll
  for (int j = 0; j < BLOADS; ++j) stageB(0, 0, j);
  asm volatile("s_waitcnt vmcnt(0)" ::: "memory");
  asm volatile("s_barrier" ::: "memory");

  const int KT = K >> 6;
  for (int t = 0; t < KT; ++t) {
    const int buf = t & 1, nbuf = buf ^ 1;
    const int k1 = (t + 1) << 6;
    const bool pf = (t + 1 < KT);
    const __bf16* Ab = &Al[buf][0];
    const __bf16* Bb = &Bl[buf][0];
    bf16x8 af[2][4], bv[2][NRq];
#pragma unroll
    for (int q = 0; q < 4; ++q) {
      const int rh = q >> 1, ch = q & 1;
      if ((q & 1) == 0) {  // A-frags for this row-half (reused by the next ch-phase)
#pragma unroll
        for (int ks = 0; ks < 2; ++ks)
#pragma unroll
          for (int m = 0; m < 4; ++m)
            af[ks][m] = *(const bf16x8*)(Ab + (wr * 128 + rh * 64 + m * 16 + lr) * 64 + ks * 32 + g * 8);
      }
#pragma unroll
      for (int ks = 0; ks < 2; ++ks)
#pragma unroll
        for (int n = 0; n < NRq; ++n)
          bv[ks][n] = *(const bf16x8*)(Bb + (wc * (BN / 4) + ch * (BN / 8) + n * 16 + lr) * 64 + ks * 32 + g * 8);
      if (pf) {  // front-loaded staging into the other buffer
        if (q == 0) { stageA(nbuf, k1, 0); stageA(nbuf, k1, 1); if (BLOADS == 4) stageB(nbuf, k1, 0); }
        if (q == 1) { stageA(nbuf, k1, 2); stageA(nbuf, k1, 3); if (BLOADS == 4) stageB(nbuf, k1, 1); }
        if (q == 2) {
          if (BLOADS == 4) { stageB(nbuf, k1, 2); stageB(nbuf, k1, 3); }
          else             { stageB(nbuf, k1, 0); stageB(nbuf, k1, 1); }
        }
      }
      asm volatile("s_barrier" ::: "memory");
      asm volatile("s_waitcnt lgkmcnt(0)" ::: "memory");
      __builtin_amdgcn_sched_barrier(0);
      __builtin_amdgcn_s_setprio(1);
#pragma unroll
      for (int m = 0; m < 4; ++m)
#pragma unroll
        for (int n = 0; n < NRq; ++n)
#pragma unroll
          for (int ks = 0; ks < 2; ++ks)
            acc[rh * 4 + m][ch * NRq + n] = mfma16(af[ks][m], bv[ks][n], acc[rh * 4 + m][ch * NRq + n]);
      __builtin_amdgcn_s_setprio(0);
      if (q == 3 && pf) asm volatile("s_waitcnt vmcnt(0)" ::: "memory");
      asm volatile("s_barrier" ::: "memory");
    }
  }

  // epilogue: row = m0+wr*128+M*16+g*4+r ; col = n0+wc*(BN/4)+N*16+lr
#pragma unroll
  for (int Mi = 0; Mi < 8; ++Mi) {
    int row = m0 + wr * 128 + Mi * 16 + g * 4;
#pragma unroll
    for (int Ni = 0; Ni < BN / 64; ++Ni) {
      int col = n0 + wc * (BN / 4) + Ni * 16 + lr;
      float bvv = bias[col] * bscale;
#pragma unroll
      for (int r = 0; r < 4; ++r) {
        size_t idx = (size_t)(row + r) * N + col;
        float v = acc[Mi][Ni][r] + bvv;
        if (RES) v = nn_(v + res[idx]);
        if (OUT_BF16) ((__bf16*)out)[idx] = (__bf16)v;
        else          ((float*)out)[idx] = v;
      }
    }
  }
}

// ------------- per-head V transpose: KV_bf[B*NK][2048] -> Vt[(b*H+h)*64+d][NK] -------------
// Vt rows are chunk-swizzled per 128B tile-segment (rule #21: linear gload_lds dest +
// pre-swizzled source + swizzled read).
__global__ __launch_bounds__(256) void reorder_v_k(const __bf16* __restrict__ kv,
                                                   __bf16* __restrict__ vt) {
  __shared__ __attribute__((aligned(16))) __bf16 t[64][72];
  int bh = blockIdx.y, b = bh >> 4, h = bh & 15;
  int kk0 = blockIdx.x * 64;
  int tid = threadIdx.x;
#pragma unroll
  for (int i = 0; i < 2; i++) {
    int c = tid + i * 256;
    int kk = c >> 3, dc = c & 7;
    const __bf16* src = kv + (size_t)(b * NK_ + kk0 + kk) * 2048 + 1024 + h * 64 + dc * 8;
    *(float4*)&t[kk][dc * 8] = *(const float4*)src;
  }
  __syncthreads();
#pragma unroll
  for (int i = 0; i < 2; i++) {
    int c = tid + i * 256;
    int d = c >> 3, gch = c & 7;
    int s = gch ^ (d & 7);
    __bf16 tmp[8] __attribute__((aligned(16)));
#pragma unroll
    for (int j = 0; j < 8; j++) tmp[j] = t[s * 8 + j][d];
    __bf16* dst = vt + ((size_t)bh * 64 + d) * (size_t)NK_ + kk0 + gch * 8;
    *(float4*)dst = *(float4*)tmp;
  }
}

// ---------------- flash attention: staged LDS + swapped QK^T + 2-phase pipeline ----------------
// Q is prescaled by SCALE*log2(e) at projection time -> S is already log2-domain.
__global__ __launch_bounds__(256) void attn_k(const __bf16* __restrict__ Qg,
                                              const __bf16* __restrict__ KVg,
                                              const __bf16* __restrict__ Vt,
                                              __bf16* __restrict__ AO) {
  __shared__ __attribute__((aligned(16))) __bf16 Kt[2][64 * 64];
  __shared__ __attribute__((aligned(16))) __bf16 Vl[2][64 * 64];
  __shared__ __attribute__((aligned(16))) __bf16 Pl[4][16 * 64];
  const int tid = threadIdx.x, lane = tid & 63, wid = tid >> 6;
  const int g = lane >> 4, lr = lane & 15;
  const int bid = blockIdx.x;
  const int bh = bid & 63, b = bh >> 4, h = bh & 15;
  const int qbase = (bid >> 6) * 64 + wid * 16;

  bf16x8 qf[2];
  {
    const __bf16* qp = Qg + ((size_t)(b * NQ_ + qbase + lr)) * 1024 + h * 64 + g * 8;
    qf[0] = *(const bf16x8*)qp;
    qf[1] = *(const bf16x8*)(qp + 32);
  }

  const f32x4 zero4 = {0.f, 0.f, 0.f, 0.f};
  f32x4 po[4];
#pragma unroll
  for (int df = 0; df < 4; df++) po[df] = zero4;
  float m2 = -1e30f, l = 0.f;

  char* pw = (char*)&Pl[wid][0];
  const int swz = (lr & 7) << 4;
  int wa[4], ra[2];
#pragma unroll
  for (int n = 0; n < 4; n++) wa[n] = lr * 128 + ((n * 32 + g * 8) ^ swz);
#pragma unroll
  for (int ks = 0; ks < 2; ks++) ra[ks] = lr * 128 + ((ks * 64 + g * 16) ^ swz);

  const int kkw = wid * 16 + (lane >> 3);
  const int cc = lane & 7;
  const __bf16* Ksrc = KVg + (size_t)b * NK_ * 2048 + h * 64;
  const __bf16* Vsrc = Vt + (size_t)bh * 64 * (size_t)NK_;

#define STAGE_(bi, kv0)                                                              \
  {                                                                                  \
    _Pragma("unroll") for (int i = 0; i < 2; i++) {                                  \
      int kk = kkw + i * 8;                                                          \
      gload_lds16(Ksrc + (size_t)((kv0) + kk) * 2048 + ((cc ^ (kk & 7)) << 3),       \
                  (char*)&Kt[bi][0] + wid * 2048 + i * 1024);                        \
      gload_lds16(Vsrc + (size_t)kk * NK_ + (kv0) + (cc << 3),                       \
                  (char*)&Vl[bi][0] + wid * 2048 + i * 1024);                        \
    }                                                                                \
  }

  int cur = 0;
  STAGE_(0, 0);

  for (int t = 0; t < NK_ / 64; ++t) {
    const int kv0 = t << 6;
    if (t < NK_ / 64 - 1) {
      STAGE_(cur ^ 1, kv0 + 64);
      asm volatile("s_waitcnt vmcnt(4)" ::: "memory");
    } else {
      asm volatile("s_waitcnt vmcnt(0)" ::: "memory");
    }
    asm volatile("s_barrier" ::: "memory");

    const char* Kb = (const char*)&Kt[cur][0];
    const char* Vb = (const char*)&Vl[cur][0];

    f32x4 sa[4];
    __builtin_amdgcn_s_setprio(1);
#pragma unroll
    for (int n = 0; n < 4; n++) {
      sa[n] = zero4;
      int kk = n * 16 + lr;
#pragma unroll
      for (int ds = 0; ds < 2; ds++) {
        bf16x8 kf = *(const bf16x8*)(Kb + kk * 128 + ((ds * 64 + g * 16) ^ ((kk & 7) << 4)));
        sa[n] = mfma16(kf, qf[ds], sa[n]);
      }
    }
    __builtin_amdgcn_s_setprio(0);

    // row max (already log2-domain)
    float mx = -1e30f;
#pragma unroll
    for (int n = 0; n < 4; n++)
#pragma unroll
      for (int r = 0; r < 4; r++) mx = fmaxf(mx, sa[n][r]);
    mx = fmaxf(mx, __shfl_xor(mx, 16));
    mx = fmaxf(mx, __shfl_xor(mx, 32));

    if (__any(mx > m2 + 11.0f)) {
      float mn = fmaxf(m2, mx);
      float alpha = exp2_(m2 - mn);
      m2 = mn;
      l *= alpha;
#pragma unroll
      for (int r = 0; r < 4; r++) {
        float ar = __shfl(alpha, g * 4 + r);
#pragma unroll
        for (int df = 0; df < 4; df++) po[df][r] *= ar;
      }
    }

    float rs = 0.f;
#pragma unroll
    for (int n = 0; n < 4; n++) {
      union { __bf16 hh[4]; uint2 u; } qd;
#pragma unroll
      for (int r = 0; r < 4; r++) {
        float p = exp2_(sa[n][r] - m2);
        rs += p;
        qd.hh[r] = (__bf16)p;
      }
      *(uint2*)(pw + wa[n]) = qd.u;
    }
    rs += __shfl_xor(rs, 16);
    rs += __shfl_xor(rs, 32);
    l += rs;

    asm volatile("s_waitcnt lgkmcnt(0)" ::: "memory");

    bf16x8 pa[2];
#pragma unroll
    for (int ks = 0; ks < 2; ks++) pa[ks] = *(const bf16x8*)(pw + ra[ks]);

    __builtin_amdgcn_s_setprio(1);
#pragma unroll
    for (int df = 0; df < 4; df++) {
      int d = df * 16 + lr;
#pragma unroll
      for (int ks = 0; ks < 2; ks++) {
        bf16x8 vf = *(const bf16x8*)(Vb + d * 128 + ((ks * 64 + g * 16) ^ ((d & 7) << 4)));
        po[df] = mfma16(pa[ks], vf, po[df]);
      }
    }
    __builtin_amdgcn_s_setprio(0);

    asm volatile("s_barrier" ::: "memory");
    cur ^= 1;
  }

  float inv = 1.0f / l;
#pragma unroll
  for (int r = 0; r < 4; r++) {
    float ir = __shfl(inv, g * 4 + r);
    size_t row = (size_t)(b * NQ_ + qbase + g * 4 + r);
#pragma unroll
    for (int df = 0; df < 4; df++)
      AO[row * 1024 + h * 64 + df * 16 + lr] = (__bf16)(po[df][r] * ir);
  }
#undef STAGE_
}

extern "C" void kernel_launch(void* const* d_in, const int* in_sizes, int n_in,
                              void* d_out, int out_size, void* d_ws, size_t ws_size,
                              hipStream_t stream) {
  (void)in_sizes; (void)n_in; (void)out_size; (void)ws_size;
  const float* x_q  = (const float*)d_in[0];
  const float* x_kv = (const float*)d_in[1];
  const float* Wq   = (const float*)d_in[2];
  const float* bq   = (const float*)d_in[3];
  const float* Wkv  = (const float*)d_in[4];
  const float* bkv  = (const float*)d_in[5];
  const float* Wp   = (const float*)d_in[6];
  const float* bp   = (const float*)d_in[7];

  char* w = (char*)d_ws;
  __bf16* xq_bf  = (__bf16*)w; w += (size_t)8388608 * 2;   // [8192][1024]
  __bf16* xkv_bf = (__bf16*)w; w += (size_t)8388608 * 2;   // [8192][1024]
  __bf16* Wq_t   = (__bf16*)w; w += (size_t)1048576 * 2;   // [1024][1024]
  __bf16* Wkv_t  = (__bf16*)w; w += (size_t)2097152 * 2;   // [2048][1024]
  __bf16* Wp_t   = (__bf16*)w; w += (size_t)1048576 * 2;   // [1024][1024]
  __bf16* Q_bf   = (__bf16*)w; w += (size_t)8388608 * 2;   // [8192][1024]
  __bf16* KV_bf  = (__bf16*)w; w += (size_t)16777216 * 2;  // [8192][2048]
  __bf16* Vt     = (__bf16*)w; w += (size_t)8388608 * 2;   // [64*64][2048]
  __bf16* AO     = (__bf16*)w; w += (size_t)8388608 * 2;   // [8192][1024]

  const float C2 = SCALE_ * 1.44269504089f;  // fold softmax scale+log2e into Q projection

  cvt_bf16_k<<<8192, 256, 0, stream>>>(x_q, xq_bf, 8388608);
  cvt_bf16_k<<<8192, 256, 0, stream>>>(x_kv, xkv_bf, 8388608);
  transpose_cvt_k<<<dim3(32, 32), dim3(32, 8), 0, stream>>>(Wq, Wq_t, 1024, 1024, C2);
  transpose_cvt_k<<<dim3(64, 32), dim3(32, 8), 0, stream>>>(Wkv, Wkv_t, 1024, 2048, 1.0f);
  transpose_cvt_k<<<dim3(32, 32), dim3(32, 8), 0, stream>>>(Wp, Wp_t, 1024, 1024, 1.0f);

  gemm256_k<128, true, false><<<dim3(8, 32), 512, 0, stream>>>(xq_bf, Wq_t, bq, C2, nullptr, Q_bf, 8192, 1024, 1024);
  gemm256_k<256, true, false><<<dim3(8, 32), 512, 0, stream>>>(xkv_bf, Wkv_t, bkv, 1.0f, nullptr, KV_bf, 8192, 2048, 1024);
  reorder_v_k<<<dim3(32, 64), 256, 0, stream>>>(KV_bf, Vt);
  attn_k<<<2048, 256, 0, stream>>>(Q_bf, KV_bf, Vt, AO);
  gemm256_k<128, false, true><<<dim3(8, 32), 512, 0, stream>>>(AO, Wp_t, bp, 1.0f, x_q, d_out, 8192, 1024, 1024);
}

// Round 5
// 390.540 us; speedup vs baseline: 1.0617x; 1.0617x over previous
//
#include <hip/hip_runtime.h>
#include <hip/hip_bf16.h>

// Problem constants
#define B_   4
#define NQ_  2048
#define NK_  2048
#define D_   1024
#define H_   16
#define DH_  64
#define SCALE_ 0.125f

typedef __attribute__((ext_vector_type(8))) __bf16 bf16x8;
typedef __attribute__((ext_vector_type(4))) float  f32x4;

typedef const __attribute__((address_space(1))) unsigned int* gas1p;
typedef __attribute__((address_space(3))) unsigned int*       las3p;

__device__ __forceinline__ f32x4 mfma16(bf16x8 a, bf16x8 b, f32x4 c) {
  return __builtin_amdgcn_mfma_f32_16x16x32_bf16(a, b, c, 0, 0, 0);
}
__device__ __forceinline__ void gload_lds16(const void* g, void* l) {
  __builtin_amdgcn_global_load_lds((gas1p)g, (las3p)l, 16, 0, 0);
}
__device__ __forceinline__ float nn_(float x) {
  if (__builtin_isnan(x)) return 0.0f;
  if (__builtin_isinf(x)) return x > 0.f ? 3.402823466e38f : -3.402823466e38f;
  return x;
}
__device__ __forceinline__ float exp2_(float x) {
#if __has_builtin(__builtin_amdgcn_exp2f)
  return __builtin_amdgcn_exp2f(x);
#else
  return __expf(x * 0.69314718056f);
#endif
}

// ---------------- fp32 -> bf16 convert (vectorized) ----------------
__global__ __launch_bounds__(256) void cvt_bf16_k(const float* __restrict__ s,
                                                  __bf16* __restrict__ d, int n) {
  int i = (blockIdx.x * blockDim.x + threadIdx.x) << 2;
  if (i >= n) return;
  float4 v = *(const float4*)(s + i);
  __bf16 o[4] __attribute__((aligned(8))) = {(__bf16)v.x, (__bf16)v.y, (__bf16)v.z, (__bf16)v.w};
  *(uint2*)(d + i) = *(uint2*)o;
}

// ------------- weight transpose + convert + scale: src[K][N] -> dst[N][K] -------------
__global__ __launch_bounds__(256) void transpose_cvt_k(const float* __restrict__ src,
                                                       __bf16* __restrict__ dst,
                                                       int K, int N, float scale) {
  __shared__ float t[32][33];
  int n0 = blockIdx.x * 32, k0 = blockIdx.y * 32;
  int x = threadIdx.x, y0 = threadIdx.y;
  for (int yy = y0; yy < 32; yy += 8)
    t[yy][x] = src[(size_t)(k0 + yy) * N + n0 + x];
  __syncthreads();
  for (int yy = y0; yy < 32; yy += 8)
    dst[(size_t)(n0 + yy) * K + k0 + x] = (__bf16)(t[x][yy] * scale);
}

// ---------------- 3-buffer pipelined GEMM: C[M][N] = A[M][K] @ Bt[N][K]^T + bias ----------------
// BM=256, BN=128, BK=32, 512 threads = 8 waves (4M x 2N), per-wave output 64x64.
// LDS: 3 rotating buffers (72KB total -> 2 blocks/CU). Tile t reads buf t%3 while staging
// tile t+2 into buf (t+2)%3 (2 tiles from any reader -> race-free for any landing time).
// Counted s_waitcnt vmcnt(3) at tile end (never 0 mid-loop, T4); ONE barrier per tile.
// A/B LDS reads XOR-swizzled (byte ^= (row&3)<<4) via pre-swizzled global source (T2/rule 21).
template <bool OUT_BF16, bool RES>
__global__ __launch_bounds__(512, 4) void gemm3p_k(const __bf16* __restrict__ A,
                                                   const __bf16* __restrict__ Bt,
                                                   const float* __restrict__ bias, float bscale,
                                                   const float* __restrict__ res,
                                                   void* __restrict__ out,
                                                   int M, int N, int K) {
  constexpr int BM = 256, BN = 128, BK = 32;
  __shared__ __attribute__((aligned(16))) __bf16 Al[3][BM * BK];  // 16KB each
  __shared__ __attribute__((aligned(16))) __bf16 Bl[3][BN * BK];  // 8KB each
  const int tid = threadIdx.x, lane = tid & 63, wid = tid >> 6;
  const int wr = wid >> 1, wc = wid & 1;
  const int g = lane >> 4, lr = lane & 15;
  const int m0 = blockIdx.y * BM, n0 = blockIdx.x * BN;

  // staging: 16B chunks; A: 256 rows x 4 chunks = 1024 -> 2/thread; B: 512 -> 1/thread.
  // source column pre-swizzled (cc ^ (row&3)) so linear LDS dest + swizzled read works.
  const int ca1 = tid + 512;
  const int rowA0 = tid >> 2, rowA1 = ca1 >> 2, rowB = tid >> 2;
  const __bf16* aSrc0 = A + (size_t)(m0 + rowA0) * K + (((tid & 3) ^ (rowA0 & 3)) << 3);
  const __bf16* aSrc1 = A + (size_t)(m0 + rowA1) * K + (((ca1 & 3) ^ (rowA1 & 3)) << 3);
  const __bf16* bSrc  = Bt + (size_t)(n0 + rowB) * K + (((tid & 3) ^ (rowB & 3)) << 3);
  char* aDst0 = (char*)&Al[0][0] + (tid << 4);
  char* aDst1 = (char*)&Al[0][0] + (ca1 << 4);
  char* bDst  = (char*)&Bl[0][0] + (tid << 4);

  // fragment read byte-offsets (within one buffer), swizzled
  const int swz = (lr & 3) << 4;
  int offA[4], offB[4];
#pragma unroll
  for (int m = 0; m < 4; m++) offA[m] = (wr * 64 + m * 16 + lr) * 64 + ((g * 16) ^ swz);
#pragma unroll
  for (int n = 0; n < 4; n++) offB[n] = (wc * 64 + n * 16 + lr) * 64 + ((g * 16) ^ swz);

  const f32x4 zero4 = {0.f, 0.f, 0.f, 0.f};
  f32x4 acc[4][4];
#pragma unroll
  for (int m = 0; m < 4; m++)
#pragma unroll
    for (int n = 0; n < 4; n++) acc[m][n] = zero4;

  // prologue: stage tiles 0 and 1
  gload_lds16(aSrc0, aDst0); gload_lds16(aSrc1, aDst1); gload_lds16(bSrc, bDst);
  gload_lds16(aSrc0 + BK, aDst0 + 16384); gload_lds16(aSrc1 + BK, aDst1 + 16384);
  gload_lds16(bSrc + BK, bDst + 8192);
  asm volatile("s_waitcnt vmcnt(3)" ::: "memory");  // tile 0 landed (tile 1 in flight)
  __builtin_amdgcn_s_barrier();

  const int KT = K / BK;
  int cb = 0, b2 = 2;
  for (int t = 0; t < KT; ++t) {
    const char* Ab = (const char*)&Al[0][0] + cb * 16384;
    const char* Bb = (const char*)&Bl[0][0] + cb * 8192;
    bf16x8 af[4], bv[4];
#pragma unroll
    for (int m = 0; m < 4; m++) af[m] = *(const bf16x8*)(Ab + offA[m]);
#pragma unroll
    for (int n = 0; n < 4; n++) bv[n] = *(const bf16x8*)(Bb + offB[n]);
    if (t < KT - 2) {  // stage tile t+2 into buf 2 tiles away from any reader
      const int k2 = (t + 2) * BK;
      gload_lds16(aSrc0 + k2, aDst0 + b2 * 16384);
      gload_lds16(aSrc1 + k2, aDst1 + b2 * 16384);
      gload_lds16(bSrc + k2, bDst + b2 * 8192);
    }
    asm volatile("s_waitcnt lgkmcnt(0)" ::: "memory");
    __builtin_amdgcn_sched_barrier(0);
    __builtin_amdgcn_s_setprio(1);
#pragma unroll
    for (int m = 0; m < 4; m++)
#pragma unroll
      for (int n = 0; n < 4; n++) acc[m][n] = mfma16(af[m], bv[n], acc[m][n]);
    __builtin_amdgcn_s_setprio(0);
    if (t < KT - 2)       asm volatile("s_waitcnt vmcnt(3)" ::: "memory");  // t+1 landed
    else if (t == KT - 2) asm volatile("s_waitcnt vmcnt(0)" ::: "memory");  // last tile landed
    if (t < KT - 1) __builtin_amdgcn_s_barrier();
    cb = (cb == 2) ? 0 : cb + 1;
    b2 = (b2 == 2) ? 0 : b2 + 1;
  }

  // epilogue: row = m0+wr*64+Mi*16+g*4+r ; col = n0+wc*64+Ni*16+lr
#pragma unroll
  for (int Mi = 0; Mi < 4; ++Mi) {
    int row = m0 + wr * 64 + Mi * 16 + g * 4;
#pragma unroll
    for (int Ni = 0; Ni < 4; ++Ni) {
      int col = n0 + wc * 64 + Ni * 16 + lr;
      float bvv = bias[col] * bscale;
#pragma unroll
      for (int r = 0; r < 4; ++r) {
        size_t idx = (size_t)(row + r) * N + col;
        float v = acc[Mi][Ni][r] + bvv;
        if (RES) v = nn_(v + res[idx]);
        if (OUT_BF16) ((__bf16*)out)[idx] = (__bf16)v;
        else          ((float*)out)[idx] = v;
      }
    }
  }
}

// ------------- per-head V transpose: KV_bf[B*NK][2048] -> Vt[(b*H+h)*64+d][NK] -------------
// Vt rows are chunk-swizzled per 128B tile-segment (rule #21: linear gload_lds dest +
// pre-swizzled source + swizzled read).
__global__ __launch_bounds__(256) void reorder_v_k(const __bf16* __restrict__ kv,
                                                   __bf16* __restrict__ vt) {
  __shared__ __attribute__((aligned(16))) __bf16 t[64][72];
  int bh = blockIdx.y, b = bh >> 4, h = bh & 15;
  int kk0 = blockIdx.x * 64;
  int tid = threadIdx.x;
#pragma unroll
  for (int i = 0; i < 2; i++) {
    int c = tid + i * 256;
    int kk = c >> 3, dc = c & 7;
    const __bf16* src = kv + (size_t)(b * NK_ + kk0 + kk) * 2048 + 1024 + h * 64 + dc * 8;
    *(float4*)&t[kk][dc * 8] = *(const float4*)src;
  }
  __syncthreads();
#pragma unroll
  for (int i = 0; i < 2; i++) {
    int c = tid + i * 256;
    int d = c >> 3, gch = c & 7;
    int s = gch ^ (d & 7);
    __bf16 tmp[8] __attribute__((aligned(16)));
#pragma unroll
    for (int j = 0; j < 8; j++) tmp[j] = t[s * 8 + j][d];
    __bf16* dst = vt + ((size_t)bh * 64 + d) * (size_t)NK_ + kk0 + gch * 8;
    *(float4*)dst = *(float4*)tmp;
  }
}

// ---------------- flash attention: staged LDS + swapped QK^T + 2-phase pipeline ----------------
// Q is prescaled by SCALE*log2(e) at projection time -> S is already log2-domain.
__global__ __launch_bounds__(256) void attn_k(const __bf16* __restrict__ Qg,
                                              const __bf16* __restrict__ KVg,
                                              const __bf16* __restrict__ Vt,
                                              __bf16* __restrict__ AO) {
  __shared__ __attribute__((aligned(16))) __bf16 Kt[2][64 * 64];
  __shared__ __attribute__((aligned(16))) __bf16 Vl[2][64 * 64];
  __shared__ __attribute__((aligned(16))) __bf16 Pl[4][16 * 64];
  const int tid = threadIdx.x, lane = tid & 63, wid = tid >> 6;
  const int g = lane >> 4, lr = lane & 15;
  const int bid = blockIdx.x;
  const int bh = bid & 63, b = bh >> 4, h = bh & 15;
  const int qbase = (bid >> 6) * 64 + wid * 16;

  bf16x8 qf[2];
  {
    const __bf16* qp = Qg + ((size_t)(b * NQ_ + qbase + lr)) * 1024 + h * 64 + g * 8;
    qf[0] = *(const bf16x8*)qp;
    qf[1] = *(const bf16x8*)(qp + 32);
  }

  const f32x4 zero4 = {0.f, 0.f, 0.f, 0.f};
  f32x4 po[4];
#pragma unroll
  for (int df = 0; df < 4; df++) po[df] = zero4;
  float m2 = -1e30f, l = 0.f;

  char* pw = (char*)&Pl[wid][0];
  const int swz = (lr & 7) << 4;
  int wa[4], ra[2];
#pragma unroll
  for (int n = 0; n < 4; n++) wa[n] = lr * 128 + ((n * 32 + g * 8) ^ swz);
#pragma unroll
  for (int ks = 0; ks < 2; ks++) ra[ks] = lr * 128 + ((ks * 64 + g * 16) ^ swz);

  const int kkw = wid * 16 + (lane >> 3);
  const int cc = lane & 7;
  const __bf16* Ksrc = KVg + (size_t)b * NK_ * 2048 + h * 64;
  const __bf16* Vsrc = Vt + (size_t)bh * 64 * (size_t)NK_;

#define STAGE_(bi, kv0)                                                              \
  {                                                                                  \
    _Pragma("unroll") for (int i = 0; i < 2; i++) {                                  \
      int kk = kkw + i * 8;                                                          \
      gload_lds16(Ksrc + (size_t)((kv0) + kk) * 2048 + ((cc ^ (kk & 7)) << 3),       \
                  (char*)&Kt[bi][0] + wid * 2048 + i * 1024);                        \
      gload_lds16(Vsrc + (size_t)kk * NK_ + (kv0) + (cc << 3),                       \
                  (char*)&Vl[bi][0] + wid * 2048 + i * 1024);                        \
    }                                                                                \
  }

  int cur = 0;
  STAGE_(0, 0);

  for (int t = 0; t < NK_ / 64; ++t) {
    const int kv0 = t << 6;
    if (t < NK_ / 64 - 1) {
      STAGE_(cur ^ 1, kv0 + 64);
      asm volatile("s_waitcnt vmcnt(4)" ::: "memory");
    } else {
      asm volatile("s_waitcnt vmcnt(0)" ::: "memory");
    }
    asm volatile("s_barrier" ::: "memory");

    const char* Kb = (const char*)&Kt[cur][0];
    const char* Vb = (const char*)&Vl[cur][0];

    f32x4 sa[4];
    __builtin_amdgcn_s_setprio(1);
#pragma unroll
    for (int n = 0; n < 4; n++) {
      sa[n] = zero4;
      int kk = n * 16 + lr;
#pragma unroll
      for (int ds = 0; ds < 2; ds++) {
        bf16x8 kf = *(const bf16x8*)(Kb + kk * 128 + ((ds * 64 + g * 16) ^ ((kk & 7) << 4)));
        sa[n] = mfma16(kf, qf[ds], sa[n]);
      }
    }
    __builtin_amdgcn_s_setprio(0);

    // row max (already log2-domain)
    float mx = -1e30f;
#pragma unroll
    for (int n = 0; n < 4; n++)
#pragma unroll
      for (int r = 0; r < 4; r++) mx = fmaxf(mx, sa[n][r]);
    mx = fmaxf(mx, __shfl_xor(mx, 16));
    mx = fmaxf(mx, __shfl_xor(mx, 32));

    if (__any(mx > m2 + 11.0f)) {
      float mn = fmaxf(m2, mx);
      float alpha = exp2_(m2 - mn);
      m2 = mn;
      l *= alpha;
#pragma unroll
      for (int r = 0; r < 4; r++) {
        float ar = __shfl(alpha, g * 4 + r);
#pragma unroll
        for (int df = 0; df < 4; df++) po[df][r] *= ar;
      }
    }

    float rs = 0.f;
#pragma unroll
    for (int n = 0; n < 4; n++) {
      union { __bf16 hh[4]; uint2 u; } qd;
#pragma unroll
      for (int r = 0; r < 4; r++) {
        float p = exp2_(sa[n][r] - m2);
        rs += p;
        qd.hh[r] = (__bf16)p;
      }
      *(uint2*)(pw + wa[n]) = qd.u;
    }
    rs += __shfl_xor(rs, 16);
    rs += __shfl_xor(rs, 32);
    l += rs;

    asm volatile("s_waitcnt lgkmcnt(0)" ::: "memory");

    bf16x8 pa[2];
#pragma unroll
    for (int ks = 0; ks < 2; ks++) pa[ks] = *(const bf16x8*)(pw + ra[ks]);

    __builtin_amdgcn_s_setprio(1);
#pragma unroll
    for (int df = 0; df < 4; df++) {
      int d = df * 16 + lr;
#pragma unroll
      for (int ks = 0; ks < 2; ks++) {
        bf16x8 vf = *(const bf16x8*)(Vb + d * 128 + ((ks * 64 + g * 16) ^ ((d & 7) << 4)));
        po[df] = mfma16(pa[ks], vf, po[df]);
      }
    }
    __builtin_amdgcn_s_setprio(0);

    asm volatile("s_barrier" ::: "memory");
    cur ^= 1;
  }

  float inv = 1.0f / l;
#pragma unroll
  for (int r = 0; r < 4; r++) {
    float ir = __shfl(inv, g * 4 + r);
    size_t row = (size_t)(b * NQ_ + qbase + g * 4 + r);
#pragma unroll
    for (int df = 0; df < 4; df++)
      AO[row * 1024 + h * 64 + df * 16 + lr] = (__bf16)(po[df][r] * ir);
  }
#undef STAGE_
}

extern "C" void kernel_launch(void* const* d_in, const int* in_sizes, int n_in,
                              void* d_out, int out_size, void* d_ws, size_t ws_size,
                              hipStream_t stream) {
  (void)in_sizes; (void)n_in; (void)out_size; (void)ws_size;
  const float* x_q  = (const float*)d_in[0];
  const float* x_kv = (const float*)d_in[1];
  const float* Wq   = (const float*)d_in[2];
  const float* bq   = (const float*)d_in[3];
  const float* Wkv  = (const float*)d_in[4];
  const float* bkv  = (const float*)d_in[5];
  const float* Wp   = (const float*)d_in[6];
  const float* bp   = (const float*)d_in[7];

  char* w = (char*)d_ws;
  __bf16* xq_bf  = (__bf16*)w; w += (size_t)8388608 * 2;   // [8192][1024]
  __bf16* xkv_bf = (__bf16*)w; w += (size_t)8388608 * 2;   // [8192][1024]
  __bf16* Wq_t   = (__bf16*)w; w += (size_t)1048576 * 2;   // [1024][1024]
  __bf16* Wkv_t  = (__bf16*)w; w += (size_t)2097152 * 2;   // [2048][1024]
  __bf16* Wp_t   = (__bf16*)w; w += (size_t)1048576 * 2;   // [1024][1024]
  __bf16* Q_bf   = (__bf16*)w; w += (size_t)8388608 * 2;   // [8192][1024]
  __bf16* KV_bf  = (__bf16*)w; w += (size_t)16777216 * 2;  // [8192][2048]
  __bf16* Vt     = (__bf16*)w; w += (size_t)8388608 * 2;   // [64*64][2048]
  __bf16* AO     = (__bf16*)w; w += (size_t)8388608 * 2;   // [8192][1024]

  const float C2 = SCALE_ * 1.44269504089f;  // fold softmax scale+log2e into Q projection

  cvt_bf16_k<<<8192, 256, 0, stream>>>(x_q, xq_bf, 8388608);
  cvt_bf16_k<<<8192, 256, 0, stream>>>(x_kv, xkv_bf, 8388608);
  transpose_cvt_k<<<dim3(32, 32), dim3(32, 8), 0, stream>>>(Wq, Wq_t, 1024, 1024, C2);
  transpose_cvt_k<<<dim3(64, 32), dim3(32, 8), 0, stream>>>(Wkv, Wkv_t, 1024, 2048, 1.0f);
  transpose_cvt_k<<<dim3(32, 32), dim3(32, 8), 0, stream>>>(Wp, Wp_t, 1024, 1024, 1.0f);

  gemm3p_k<true, false><<<dim3(8, 32), 512, 0, stream>>>(xq_bf, Wq_t, bq, C2, nullptr, Q_bf, 8192, 1024, 1024);
  gemm3p_k<true, false><<<dim3(16, 32), 512, 0, stream>>>(xkv_bf, Wkv_t, bkv, 1.0f, nullptr, KV_bf, 8192, 2048, 1024);
  reorder_v_k<<<dim3(32, 64), 256, 0, stream>>>(KV_bf, Vt);
  attn_k<<<2048, 256, 0, stream>>>(Q_bf, KV_bf, Vt, AO);
  gemm3p_k<false, true><<<dim3(8, 32), 512, 0, stream>>>(AO, Wp_t, bp, 1.0f, x_q, d_out, 8192, 1024, 1024);
}

// Round 6
// 389.902 us; speedup vs baseline: 1.0635x; 1.0016x over previous
//
#include <hip/hip_runtime.h>
#include <hip/hip_bf16.h>

// Problem constants
#define B_   4
#define NQ_  2048
#define NK_  2048
#define D_   1024
#define H_   16
#define DH_  64
#define SCALE_ 0.125f

typedef __attribute__((ext_vector_type(8))) __bf16 bf16x8;
typedef __attribute__((ext_vector_type(4))) float  f32x4;

typedef const __attribute__((address_space(1))) unsigned int* gas1p;
typedef __attribute__((address_space(3))) unsigned int*       las3p;

__device__ __forceinline__ f32x4 mfma16(bf16x8 a, bf16x8 b, f32x4 c) {
  return __builtin_amdgcn_mfma_f32_16x16x32_bf16(a, b, c, 0, 0, 0);
}
__device__ __forceinline__ void gload_lds16(const void* g, void* l) {
  __builtin_amdgcn_global_load_lds((gas1p)g, (las3p)l, 16, 0, 0);
}
__device__ __forceinline__ float nn_(float x) {
  if (__builtin_isnan(x)) return 0.0f;
  if (__builtin_isinf(x)) return x > 0.f ? 3.402823466e38f : -3.402823466e38f;
  return x;
}
__device__ __forceinline__ float exp2_(float x) {
#if __has_builtin(__builtin_amdgcn_exp2f)
  return __builtin_amdgcn_exp2f(x);
#else
  return __expf(x * 0.69314718056f);
#endif
}
__device__ __forceinline__ float fmax3_(float a, float b, float c) {
  return fmaxf(fmaxf(a, b), c);  // clang fuses to v_max3_f32
}

// ---------------- fp32 -> bf16 convert (vectorized) ----------------
__global__ __launch_bounds__(256) void cvt_bf16_k(const float* __restrict__ s,
                                                  __bf16* __restrict__ d, int n) {
  int i = (blockIdx.x * blockDim.x + threadIdx.x) << 2;
  if (i >= n) return;
  float4 v = *(const float4*)(s + i);
  __bf16 o[4] __attribute__((aligned(8))) = {(__bf16)v.x, (__bf16)v.y, (__bf16)v.z, (__bf16)v.w};
  *(uint2*)(d + i) = *(uint2*)o;
}

// ------------- weight transpose + convert + scale: src[K][N] -> dst[N][K] -------------
__global__ __launch_bounds__(256) void transpose_cvt_k(const float* __restrict__ src,
                                                       __bf16* __restrict__ dst,
                                                       int K, int N, float scale) {
  __shared__ float t[32][33];
  int n0 = blockIdx.x * 32, k0 = blockIdx.y * 32;
  int x = threadIdx.x, y0 = threadIdx.y;
  for (int yy = y0; yy < 32; yy += 8)
    t[yy][x] = src[(size_t)(k0 + yy) * N + n0 + x];
  __syncthreads();
  for (int yy = y0; yy < 32; yy += 8)
    dst[(size_t)(n0 + yy) * K + k0 + x] = (__bf16)(t[x][yy] * scale);
}

// ---------------- 3-buffer pipelined GEMM: C[M][N] = A[M][K] @ Bt[N][K]^T + bias ----------------
// BM=256, BN=128, BK=32, 512 threads = 8 waves (4M x 2N), per-wave output 64x64.
// 3 rotating LDS buffers (72KB -> 2 blocks/CU). Tile t reads buf t%3 while staging tile t+2
// into buf (t+2)%3. Counted vmcnt(3) (T4); ONE barrier per tile. NO manual lgkmcnt: the
// compiler emits fine-grained counted lgkmcnt interleaving ds_reads with the MFMA cluster.
template <bool OUT_BF16, bool RES>
__global__ __launch_bounds__(512, 4) void gemm3p_k(const __bf16* __restrict__ A,
                                                   const __bf16* __restrict__ Bt,
                                                   const float* __restrict__ bias, float bscale,
                                                   const float* __restrict__ res,
                                                   void* __restrict__ out,
                                                   int M, int N, int K) {
  constexpr int BM = 256, BN = 128, BK = 32;
  __shared__ __attribute__((aligned(16))) __bf16 Al[3][BM * BK];  // 16KB each
  __shared__ __attribute__((aligned(16))) __bf16 Bl[3][BN * BK];  // 8KB each
  const int tid = threadIdx.x, lane = tid & 63, wid = tid >> 6;
  const int wr = wid >> 1, wc = wid & 1;
  const int g = lane >> 4, lr = lane & 15;
  const int m0 = blockIdx.y * BM, n0 = blockIdx.x * BN;

  // staging: 16B chunks; source column pre-swizzled (cc ^ (row&3)) -> swizzled LDS read (rule 21)
  const int ca1 = tid + 512;
  const int rowA0 = tid >> 2, rowA1 = ca1 >> 2, rowB = tid >> 2;
  const __bf16* aSrc0 = A + (size_t)(m0 + rowA0) * K + (((tid & 3) ^ (rowA0 & 3)) << 3);
  const __bf16* aSrc1 = A + (size_t)(m0 + rowA1) * K + (((ca1 & 3) ^ (rowA1 & 3)) << 3);
  const __bf16* bSrc  = Bt + (size_t)(n0 + rowB) * K + (((tid & 3) ^ (rowB & 3)) << 3);
  char* aDst0 = (char*)&Al[0][0] + (tid << 4);
  char* aDst1 = (char*)&Al[0][0] + (ca1 << 4);
  char* bDst  = (char*)&Bl[0][0] + (tid << 4);

  const int swz = (lr & 3) << 4;
  int offA[4], offB[4];
#pragma unroll
  for (int m = 0; m < 4; m++) offA[m] = (wr * 64 + m * 16 + lr) * 64 + ((g * 16) ^ swz);
#pragma unroll
  for (int n = 0; n < 4; n++) offB[n] = (wc * 64 + n * 16 + lr) * 64 + ((g * 16) ^ swz);

  const f32x4 zero4 = {0.f, 0.f, 0.f, 0.f};
  f32x4 acc[4][4];
#pragma unroll
  for (int m = 0; m < 4; m++)
#pragma unroll
    for (int n = 0; n < 4; n++) acc[m][n] = zero4;

  // prologue: stage tiles 0 and 1
  gload_lds16(aSrc0, aDst0); gload_lds16(aSrc1, aDst1); gload_lds16(bSrc, bDst);
  gload_lds16(aSrc0 + BK, aDst0 + 16384); gload_lds16(aSrc1 + BK, aDst1 + 16384);
  gload_lds16(bSrc + BK, bDst + 8192);
  asm volatile("s_waitcnt vmcnt(3)" ::: "memory");  // tile 0 landed (tile 1 in flight)
  __builtin_amdgcn_s_barrier();

  const int KT = K / BK;
  int cb = 0, b2 = 2;
  for (int t = 0; t < KT; ++t) {
    const char* Ab = (const char*)&Al[0][0] + cb * 16384;
    const char* Bb = (const char*)&Bl[0][0] + cb * 8192;
    bf16x8 af[4], bv[4];
#pragma unroll
    for (int m = 0; m < 4; m++) af[m] = *(const bf16x8*)(Ab + offA[m]);
#pragma unroll
    for (int n = 0; n < 4; n++) bv[n] = *(const bf16x8*)(Bb + offB[n]);
    if (t < KT - 2) {  // stage tile t+2 (2 tiles from any reader -> race-free)
      const int k2 = (t + 2) * BK;
      gload_lds16(aSrc0 + k2, aDst0 + b2 * 16384);
      gload_lds16(aSrc1 + k2, aDst1 + b2 * 16384);
      gload_lds16(bSrc + k2, bDst + b2 * 8192);
    }
    // compiler inserts counted lgkmcnt between ds_reads and dependent MFMAs
    __builtin_amdgcn_s_setprio(1);
#pragma unroll
    for (int m = 0; m < 4; m++)
#pragma unroll
      for (int n = 0; n < 4; n++) acc[m][n] = mfma16(af[m], bv[n], acc[m][n]);
    __builtin_amdgcn_s_setprio(0);
    if (t < KT - 2)       asm volatile("s_waitcnt vmcnt(3)" ::: "memory");  // t+1 landed
    else if (t == KT - 2) asm volatile("s_waitcnt vmcnt(0)" ::: "memory");
    if (t < KT - 1) __builtin_amdgcn_s_barrier();
    cb = (cb == 2) ? 0 : cb + 1;
    b2 = (b2 == 2) ? 0 : b2 + 1;
  }

  // epilogue
#pragma unroll
  for (int Mi = 0; Mi < 4; ++Mi) {
    int row = m0 + wr * 64 + Mi * 16 + g * 4;
#pragma unroll
    for (int Ni = 0; Ni < 4; ++Ni) {
      int col = n0 + wc * 64 + Ni * 16 + lr;
      float bvv = bias[col] * bscale;
#pragma unroll
      for (int r = 0; r < 4; ++r) {
        size_t idx = (size_t)(row + r) * N + col;
        float v = acc[Mi][Ni][r] + bvv;
        if (RES) v = nn_(v + res[idx]);
        if (OUT_BF16) ((__bf16*)out)[idx] = (__bf16)v;
        else          ((float*)out)[idx] = v;
      }
    }
  }
}

// ------------- per-head V transpose: KV_bf[B*NK][2048] -> Vt[(b*H+h)*64+d][NK] -------------
__global__ __launch_bounds__(256) void reorder_v_k(const __bf16* __restrict__ kv,
                                                   __bf16* __restrict__ vt) {
  __shared__ __attribute__((aligned(16))) __bf16 t[64][72];
  int bh = blockIdx.y, b = bh >> 4, h = bh & 15;
  int kk0 = blockIdx.x * 64;
  int tid = threadIdx.x;
#pragma unroll
  for (int i = 0; i < 2; i++) {
    int c = tid + i * 256;
    int kk = c >> 3, dc = c & 7;
    const __bf16* src = kv + (size_t)(b * NK_ + kk0 + kk) * 2048 + 1024 + h * 64 + dc * 8;
    *(float4*)&t[kk][dc * 8] = *(const float4*)src;
  }
  __syncthreads();
#pragma unroll
  for (int i = 0; i < 2; i++) {
    int c = tid + i * 256;
    int d = c >> 3, gch = c & 7;
    int s = gch ^ (d & 7);
    __bf16 tmp[8] __attribute__((aligned(16)));
#pragma unroll
    for (int j = 0; j < 8; j++) tmp[j] = t[s * 8 + j][d];
    __bf16* dst = vt + ((size_t)bh * 64 + d) * (size_t)NK_ + kk0 + gch * 8;
    *(float4*)dst = *(float4*)tmp;
  }
}

// ---------------- flash attention: staged LDS + swapped QK^T, VALU-trimmed ----------------
// 1D grid 2048 blocks: bh=bid&63 (head->XCD pinning). 4 waves x 16 q-rows, KVBLK=64,
// K/V double-buffered. Per tile: STAGE(next,ptr+=const) -> vmcnt(4) -> barrier -> QK^T ->
// softmax(max3 tree) -> P round-trip -> PV -> barrier. 2-tile unroll (compile-time buffers);
// staging via running pointers (no per-tile address math). Q prescaled by SCALE*log2e.
__global__ __launch_bounds__(256) void attn_k(const __bf16* __restrict__ Qg,
                                              const __bf16* __restrict__ KVg,
                                              const __bf16* __restrict__ Vt,
                                              __bf16* __restrict__ AO) {
  __shared__ __attribute__((aligned(16))) __bf16 Kt[2][64 * 64];
  __shared__ __attribute__((aligned(16))) __bf16 Vl[2][64 * 64];
  __shared__ __attribute__((aligned(16))) __bf16 Pl[4][16 * 64];
  const int tid = threadIdx.x, lane = tid & 63, wid = tid >> 6;
  const int g = lane >> 4, lr = lane & 15;
  const int bid = blockIdx.x;
  const int bh = bid & 63, b = bh >> 4, h = bh & 15;
  const int qbase = (bid >> 6) * 64 + wid * 16;

  bf16x8 qf[2];
  {
    const __bf16* qp = Qg + ((size_t)(b * NQ_ + qbase + lr)) * 1024 + h * 64 + g * 8;
    qf[0] = *(const bf16x8*)qp;
    qf[1] = *(const bf16x8*)(qp + 32);
  }

  const f32x4 zero4 = {0.f, 0.f, 0.f, 0.f};
  f32x4 po[4];
#pragma unroll
  for (int df = 0; df < 4; df++) po[df] = zero4;
  float m2 = -1e30f, l = 0.f;

  char* pw = (char*)&Pl[wid][0];
  const int pswz = (lr & 7) << 4;
  int wa[4], ra[2];
#pragma unroll
  for (int n = 0; n < 4; n++) wa[n] = lr * 128 + ((n * 32 + g * 8) ^ pswz);
#pragma unroll
  for (int ks = 0; ks < 2; ks++) ra[ks] = lr * 128 + ((ks * 64 + g * 16) ^ pswz);

  // running staging pointers (advance by constant stride per tile; no addr math in loop)
  const int kk = wid * 16 + (lane >> 3);
  const int cc = lane & 7;
  const __bf16* kp0 = KVg + (size_t)b * NK_ * 2048 + h * 64 + (size_t)kk * 2048 + ((cc ^ (kk & 7)) << 3);
  const __bf16* kp1 = kp0 + 8 * 2048;        // (kk+8)&7 == kk&7 -> same swizzle
  const __bf16* vp0 = Vt + (size_t)bh * 64 * (size_t)NK_ + (size_t)kk * NK_ + (cc << 3);
  const __bf16* vp1 = vp0 + 8 * NK_;
  char* kd0 = (char*)&Kt[0][0] + wid * 2048;
  char* vd0 = (char*)&Vl[0][0] + wid * 2048;

#define STAGE_(bi)                                             \
  {                                                            \
    gload_lds16(kp0, kd0 + (bi) * 8192);                       \
    gload_lds16(kp1, kd0 + (bi) * 8192 + 1024);                \
    gload_lds16(vp0, vd0 + (bi) * 8192);                       \
    gload_lds16(vp1, vd0 + (bi) * 8192 + 1024);                \
    kp0 += 64 * 2048; kp1 += 64 * 2048; vp0 += 64; vp1 += 64;  \
  }

#define BODY_(bi)                                                                              \
  {                                                                                            \
    const char* Kb = (const char*)&Kt[bi][0];                                                  \
    const char* Vb = (const char*)&Vl[bi][0];                                                  \
    f32x4 sa[4];                                                                               \
    __builtin_amdgcn_s_setprio(1);                                                             \
    _Pragma("unroll") for (int n = 0; n < 4; n++) {                                            \
      sa[n] = zero4;                                                                           \
      int kr = n * 16 + lr;                                                                    \
      _Pragma("unroll") for (int ds = 0; ds < 2; ds++) {                                       \
        bf16x8 kf = *(const bf16x8*)(Kb + kr * 128 + ((ds * 64 + g * 16) ^ ((kr & 7) << 4)));  \
        sa[n] = mfma16(kf, qf[ds], sa[n]);                                                     \
      }                                                                                        \
    }                                                                                          \
    __builtin_amdgcn_s_setprio(0);                                                             \
    float mx = fmax3_(sa[0][0], sa[0][1], sa[0][2]);                                           \
    mx = fmax3_(mx, sa[0][3], sa[1][0]);                                                       \
    mx = fmax3_(mx, sa[1][1], sa[1][2]);                                                       \
    mx = fmax3_(mx, sa[1][3], sa[2][0]);                                                       \
    mx = fmax3_(mx, sa[2][1], sa[2][2]);                                                       \
    mx = fmax3_(mx, sa[2][3], sa[3][0]);                                                       \
    mx = fmax3_(mx, sa[3][1], sa[3][2]);                                                       \
    mx = fmaxf(mx, sa[3][3]);                                                                  \
    mx = fmaxf(mx, __shfl_xor(mx, 16));                                                        \
    mx = fmaxf(mx, __shfl_xor(mx, 32));                                                        \
    if (__any(mx > m2 + 11.0f)) {                                                              \
      float mn = fmaxf(m2, mx);                                                                \
      float alpha = exp2_(m2 - mn);                                                            \
      m2 = mn;                                                                                 \
      l *= alpha;                                                                              \
      _Pragma("unroll") for (int r = 0; r < 4; r++) {                                          \
        float ar = __shfl(alpha, g * 4 + r);                                                   \
        _Pragma("unroll") for (int df = 0; df < 4; df++) po[df][r] *= ar;                      \
      }                                                                                        \
    }                                                                                          \
    float rs = 0.f;                                                                            \
    _Pragma("unroll") for (int n = 0; n < 4; n++) {                                            \
      union { __bf16 hh[4]; uint2 u; } qd;                                                     \
      _Pragma("unroll") for (int r = 0; r < 4; r++) {                                          \
        float p = exp2_(sa[n][r] - m2);                                                        \
        rs += p;                                                                               \
        qd.hh[r] = (__bf16)p;                                                                  \
      }                                                                                        \
      *(uint2*)(pw + wa[n]) = qd.u;                                                            \
    }                                                                                          \
    rs += __shfl_xor(rs, 16);                                                                  \
    rs += __shfl_xor(rs, 32);                                                                  \
    l += rs;                                                                                   \
    bf16x8 pa[2];                                                                              \
    _Pragma("unroll") for (int ks = 0; ks < 2; ks++)                                           \
      pa[ks] = *(const bf16x8*)(pw + ra[ks]);                                                  \
    __builtin_amdgcn_s_setprio(1);                                                             \
    _Pragma("unroll") for (int df = 0; df < 4; df++) {                                         \
      int d = df * 16 + lr;                                                                    \
      _Pragma("unroll") for (int ks = 0; ks < 2; ks++) {                                       \
        bf16x8 vf = *(const bf16x8*)(Vb + d * 128 + ((ks * 64 + g * 16) ^ ((d & 7) << 4)));    \
        po[df] = mfma16(pa[ks], vf, po[df]);                                                   \
      }                                                                                        \
    }                                                                                          \
    __builtin_amdgcn_s_setprio(0);                                                             \
  }

  STAGE_(0);  // tile 0 -> buf0

#pragma unroll 1
  for (int it = 0; it < 16; ++it) {
    // tile 2*it (buf0): prefetch 2*it+1 -> buf1
    STAGE_(1);
    asm volatile("s_waitcnt vmcnt(4)" ::: "memory");
    asm volatile("s_barrier" ::: "memory");
    BODY_(0);
    asm volatile("s_barrier" ::: "memory");
    // tile 2*it+1 (buf1): prefetch 2*it+2 -> buf0 (except after last tile)
    if (it < 15) {
      STAGE_(0);
      asm volatile("s_waitcnt vmcnt(4)" ::: "memory");
    } else {
      asm volatile("s_waitcnt vmcnt(0)" ::: "memory");
    }
    asm volatile("s_barrier" ::: "memory");
    BODY_(1);
    asm volatile("s_barrier" ::: "memory");
  }

  float inv = 1.0f / l;
#pragma unroll
  for (int r = 0; r < 4; r++) {
    float ir = __shfl(inv, g * 4 + r);
    size_t row = (size_t)(b * NQ_ + qbase + g * 4 + r);
#pragma unroll
    for (int df = 0; df < 4; df++)
      AO[row * 1024 + h * 64 + df * 16 + lr] = (__bf16)(po[df][r] * ir);
  }
#undef STAGE_
#undef BODY_
}

extern "C" void kernel_launch(void* const* d_in, const int* in_sizes, int n_in,
                              void* d_out, int out_size, void* d_ws, size_t ws_size,
                              hipStream_t stream) {
  (void)in_sizes; (void)n_in; (void)out_size; (void)ws_size;
  const float* x_q  = (const float*)d_in[0];
  const float* x_kv = (const float*)d_in[1];
  const float* Wq   = (const float*)d_in[2];
  const float* bq   = (const float*)d_in[3];
  const float* Wkv  = (const float*)d_in[4];
  const float* bkv  = (const float*)d_in[5];
  const float* Wp   = (const float*)d_in[6];
  const float* bp   = (const float*)d_in[7];

  char* w = (char*)d_ws;
  __bf16* xq_bf  = (__bf16*)w; w += (size_t)8388608 * 2;   // [8192][1024]
  __bf16* xkv_bf = (__bf16*)w; w += (size_t)8388608 * 2;   // [8192][1024]
  __bf16* Wq_t   = (__bf16*)w; w += (size_t)1048576 * 2;   // [1024][1024]
  __bf16* Wkv_t  = (__bf16*)w; w += (size_t)2097152 * 2;   // [2048][1024]
  __bf16* Wp_t   = (__bf16*)w; w += (size_t)1048576 * 2;   // [1024][1024]
  __bf16* Q_bf   = (__bf16*)w; w += (size_t)8388608 * 2;   // [8192][1024]
  __bf16* KV_bf  = (__bf16*)w; w += (size_t)16777216 * 2;  // [8192][2048]
  __bf16* Vt     = (__bf16*)w; w += (size_t)8388608 * 2;   // [64*64][2048]
  __bf16* AO     = (__bf16*)w; w += (size_t)8388608 * 2;   // [8192][1024]

  const float C2 = SCALE_ * 1.44269504089f;  // fold softmax scale+log2e into Q projection

  cvt_bf16_k<<<8192, 256, 0, stream>>>(x_q, xq_bf, 8388608);
  cvt_bf16_k<<<8192, 256, 0, stream>>>(x_kv, xkv_bf, 8388608);
  transpose_cvt_k<<<dim3(32, 32), dim3(32, 8), 0, stream>>>(Wq, Wq_t, 1024, 1024, C2);
  transpose_cvt_k<<<dim3(64, 32), dim3(32, 8), 0, stream>>>(Wkv, Wkv_t, 1024, 2048, 1.0f);
  transpose_cvt_k<<<dim3(32, 32), dim3(32, 8), 0, stream>>>(Wp, Wp_t, 1024, 1024, 1.0f);

  gemm3p_k<true, false><<<dim3(8, 32), 512, 0, stream>>>(xq_bf, Wq_t, bq, C2, nullptr, Q_bf, 8192, 1024, 1024);
  gemm3p_k<true, false><<<dim3(16, 32), 512, 0, stream>>>(xkv_bf, Wkv_t, bkv, 1.0f, nullptr, KV_bf, 8192, 2048, 1024);
  reorder_v_k<<<dim3(32, 64), 256, 0, stream>>>(KV_bf, Vt);
  attn_k<<<2048, 256, 0, stream>>>(Q_bf, KV_bf, Vt, AO);
  gemm3p_k<false, true><<<dim3(8, 32), 512, 0, stream>>>(AO, Wp_t, bp, 1.0f, x_q, d_out, 8192, 1024, 1024);
}